// Round 7
// baseline (186.420 us; speedup 1.0000x reference)
//
#include <hip/hip_runtime.h>
#include <stdint.h>

#define D_MODEL 1024
#define SEQ     2048
#define NHEAD   16
#define BATCH   2
#define NROWS   (BATCH*SEQ)   // 4096

typedef _Float16 f16;
typedef _Float16 f16x8 __attribute__((ext_vector_type(8)));
typedef _Float16 f16x4 __attribute__((ext_vector_type(4)));
typedef __fp16   h16x2 __attribute__((ext_vector_type(2)));
typedef float    f32x4 __attribute__((ext_vector_type(4)));

#define MFMA16 __builtin_amdgcn_mfma_f32_16x16x32_f16

__device__ __forceinline__ void gload16(const void* g, void* l) {
  __builtin_amdgcn_global_load_lds(
      (const __attribute__((address_space(1))) void*)g,
      (__attribute__((address_space(3))) void*)l, 16, 0, 0);
}

__device__ __forceinline__ int pkh2(float a, float b) {
  union { h16x2 h; int i; } u;
  u.h = __builtin_amdgcn_cvt_pkrtz(a, b);
  return u.i;
}

// ---------------- convert / split kernels ----------------
__global__ void split4_kernel(const float* __restrict__ in, f16* __restrict__ hi,
                              f16* __restrict__ lo, int n4, float scale) {
  int i = blockIdx.x * blockDim.x + threadIdx.x;
  if (i >= n4) return;
  float4 v = reinterpret_cast<const float4*>(in)[i];
  v.x *= scale; v.y *= scale; v.z *= scale; v.w *= scale;
  f16x4 h, l4;
  h[0] = (f16)v.x; h[1] = (f16)v.y; h[2] = (f16)v.z; h[3] = (f16)v.w;
  l4[0] = (f16)(v.x - (float)h[0]);
  l4[1] = (f16)(v.y - (float)h[1]);
  l4[2] = (f16)(v.z - (float)h[2]);
  l4[3] = (f16)(v.w - (float)h[3]);
  *reinterpret_cast<f16x4*>(hi + 4*(size_t)i) = h;
  *reinterpret_cast<f16x4*>(lo + 4*(size_t)i) = l4;
}

// fused weight prep: wq split (scaled), wk split, wv cvt, wo cvt — one pass
__global__ void prep_w_kernel(const float* __restrict__ pq, const float* __restrict__ pk,
                              const float* __restrict__ pv, const float* __restrict__ po,
                              f16* __restrict__ wq_hi, f16* __restrict__ wq_lo,
                              f16* __restrict__ wk_hi, f16* __restrict__ wk_lo,
                              f16* __restrict__ wv_h,  f16* __restrict__ wo_h,
                              int n4, float qscale) {
  int i = blockIdx.x * blockDim.x + threadIdx.x;
  if (i >= n4) return;
  {
    float4 v = reinterpret_cast<const float4*>(pq)[i];
    v.x *= qscale; v.y *= qscale; v.z *= qscale; v.w *= qscale;
    f16x4 h, l4;
    h[0] = (f16)v.x; h[1] = (f16)v.y; h[2] = (f16)v.z; h[3] = (f16)v.w;
    l4[0] = (f16)(v.x - (float)h[0]); l4[1] = (f16)(v.y - (float)h[1]);
    l4[2] = (f16)(v.z - (float)h[2]); l4[3] = (f16)(v.w - (float)h[3]);
    *reinterpret_cast<f16x4*>(wq_hi + 4*(size_t)i) = h;
    *reinterpret_cast<f16x4*>(wq_lo + 4*(size_t)i) = l4;
  }
  {
    float4 v = reinterpret_cast<const float4*>(pk)[i];
    f16x4 h, l4;
    h[0] = (f16)v.x; h[1] = (f16)v.y; h[2] = (f16)v.z; h[3] = (f16)v.w;
    l4[0] = (f16)(v.x - (float)h[0]); l4[1] = (f16)(v.y - (float)h[1]);
    l4[2] = (f16)(v.z - (float)h[2]); l4[3] = (f16)(v.w - (float)h[3]);
    *reinterpret_cast<f16x4*>(wk_hi + 4*(size_t)i) = h;
    *reinterpret_cast<f16x4*>(wk_lo + 4*(size_t)i) = l4;
  }
  {
    float4 v = reinterpret_cast<const float4*>(pv)[i];
    f16x4 h;
    h[0] = (f16)v.x; h[1] = (f16)v.y; h[2] = (f16)v.z; h[3] = (f16)v.w;
    *reinterpret_cast<f16x4*>(wv_h + 4*(size_t)i) = h;
  }
  {
    float4 v = reinterpret_cast<const float4*>(po)[i];
    f16x4 h;
    h[0] = (f16)v.x; h[1] = (f16)v.y; h[2] = (f16)v.z; h[3] = (f16)v.w;
    *reinterpret_cast<f16x4*>(wo_h + 4*(size_t)i) = h;
  }
}

// ---------------- GEMM: C[M,N] = A[M,K] · B[N,K]^T  (NT) ----------------
template<bool SPLIT_IN, bool SPLIT_OUT, bool F32_OUT, bool COLCHUNK>
__global__ __launch_bounds__(256, 2)
void gemm_nt(const f16* __restrict__ Ahi, const f16* __restrict__ Alo,
             const f16* __restrict__ Bhi, const f16* __restrict__ Blo,
             f16* __restrict__ Chi, f16* __restrict__ Clo, float* __restrict__ Cf,
             int M, int N, int K)
{
  constexpr int ALO_OFF = 8192;
  constexpr int B_OFF   = SPLIT_IN ? 16384 : 8192;
  constexpr int BLO_OFF = 20480;
  constexpr int STRIDE  = SPLIT_IN ? 24576 : 12288;
  __shared__ __align__(16) char smem[2 * STRIDE];

  const int tid = threadIdx.x;
  const int w = tid >> 6, l = tid & 63;
  const int wr = (w >> 1) * 64;
  const int wc = (w & 1) * 32;

  const int gx = gridDim.x, gy = gridDim.y;
  const int nwg = gx * gy;
  const int flat = blockIdx.y * gx + blockIdx.x;
  const int swz = (flat & 7) * (nwg >> 3) + (flat >> 3);
  const int bxn = COLCHUNK ? (swz / gy) : (swz % gx);
  const int byn = COLCHUNK ? (swz % gy) : (swz / gx);
  const int bm = byn * 128, bn = bxn * 64;

  f32x4 acc[4][2] = {};

  const int srow = tid >> 2;
  const int schunk = 8 * (((tid & 3) ^ ((srow >> 1) & 3)));

  auto stage = [&](int kt) {
    char* dst = smem + (kt & 1) * STRIDE;
    const int k0 = kt * 32;
    const f16* ga = Ahi + (size_t)(bm + srow) * K + k0 + schunk;
    gload16(ga,        dst + (w << 10));
    gload16(ga + 64*K, dst + 4096 + (w << 10));
    const f16* gb = Bhi + (size_t)(bn + srow) * K + k0 + schunk;
    gload16(gb,        dst + B_OFF + (w << 10));
    if (SPLIT_IN) {
      const f16* gal = Alo + (size_t)(bm + srow) * K + k0 + schunk;
      gload16(gal,        dst + ALO_OFF + (w << 10));
      gload16(gal + 64*K, dst + ALO_OFF + 4096 + (w << 10));
      const f16* gbl = Blo + (size_t)(bn + srow) * K + k0 + schunk;
      gload16(gbl,        dst + BLO_OFF + (w << 10));
    }
  };

  const int nkt = K >> 5;
  stage(0);

  for (int kt = 0; kt < nkt; kt++) {
    if (kt + 1 < nkt) {
      stage(kt + 1);
      if constexpr (SPLIT_IN) asm volatile("s_waitcnt vmcnt(6)" ::: "memory");
      else                    asm volatile("s_waitcnt vmcnt(3)" ::: "memory");
    } else {
      asm volatile("s_waitcnt vmcnt(0)" ::: "memory");
    }
    __builtin_amdgcn_s_barrier();

    const char* buf = smem + (kt & 1) * STRIDE;
    const int ar = (l & 15);
    const int ak = 16 * ((l >> 4) ^ ((ar >> 1) & 3));
    f16x8 a_hi[4], a_lo[4];
#pragma unroll
    for (int mi = 0; mi < 4; mi++) {
      a_hi[mi] = *(const f16x8*)(buf + (size_t)(wr + mi*16 + ar) * 64 + ak);
      if (SPLIT_IN)
        a_lo[mi] = *(const f16x8*)(buf + ALO_OFF + (size_t)(wr + mi*16 + ar) * 64 + ak);
    }
    __builtin_amdgcn_s_setprio(1);
#pragma unroll
    for (int ni = 0; ni < 2; ni++) {
      f16x8 b_hi = *(const f16x8*)(buf + B_OFF + (size_t)(wc + ni*16 + ar) * 64 + ak);
      f16x8 b_lo = {};
      if (SPLIT_IN)
        b_lo = *(const f16x8*)(buf + BLO_OFF + (size_t)(wc + ni*16 + ar) * 64 + ak);
#pragma unroll
      for (int mi = 0; mi < 4; mi++) {
        acc[mi][ni] = MFMA16(a_hi[mi], b_hi, acc[mi][ni], 0, 0, 0);
        if (SPLIT_IN) {
          acc[mi][ni] = MFMA16(a_hi[mi], b_lo, acc[mi][ni], 0, 0, 0);
          acc[mi][ni] = MFMA16(a_lo[mi], b_hi, acc[mi][ni], 0, 0, 0);
        }
      }
    }
    __builtin_amdgcn_s_setprio(0);
    __builtin_amdgcn_s_barrier();
  }

  const int crow0 = bm + wr + (l >> 4) * 4;
  const int ccol0 = bn + wc + (l & 15);
#pragma unroll
  for (int mi = 0; mi < 4; mi++) {
#pragma unroll
    for (int ni = 0; ni < 2; ni++) {
#pragma unroll
      for (int j = 0; j < 4; j++) {
        size_t idx = (size_t)(crow0 + mi*16 + j) * N + (ccol0 + ni*16);
        float v = acc[mi][ni][j];
        if (F32_OUT) {
          Cf[idx] = v;
        } else {
          f16 h = (f16)v;
          Chi[idx] = h;
          if (SPLIT_OUT) Clo[idx] = (f16)(v - (float)h);
        }
      }
    }
  }
}

// ---------------- flash attention v6 (causal, transposed scores, SW pipeline) --------
// QBLK=128 (8 waves x 16 q), KVBLK=64. 2-deep cross-tile software pipeline:
// S(t) lives in registers across the barrier; per iter:
//   stage(t+2) | softmax(t)+P-build | PV(t) | vmcnt;barrier | S(t+1)=QK^T | barrier
// K double-buffered (2x16KB), V TRIPLE-buffered (3x8KB, slot t%3) so PV(t) is
// legal while stage(t+2) prefetches. Defer-max: skip o/l rescale unless
// !__all(pm - m_run <= 8) (exp2-domain headroom 2^8, safe in f16 P / f32 acc).
__global__ __launch_bounds__(512, 4)
void attn_kernel(const f16* __restrict__ Qhi, const f16* __restrict__ Qlo,
                 const f16* __restrict__ Khi, const f16* __restrict__ Klo,
                 const f16* __restrict__ VT, f16* __restrict__ Out)
{
  __shared__ __align__(16) char smem[57344];   // K: 2x16KB @0; V: 3x8KB @32768

  const int tid = threadIdx.x, w = tid >> 6, l = tid & 63;
  const int g = l >> 4, q4 = l & 15;
  const int flat = blockIdx.x;
  const int xcd = flat & 7, slot = flat >> 3;
  const int r4 = slot >> 4;
  const int ii = slot & 15;
  const int bh = xcd * 4 + r4;
  const int qx = ((slot >> 5) & 1) ? (15 - ii) : ii;
  const int b = bh >> 4, h = bh & 15;
  const int q0 = qx * 128;
  const int qw = q0 + w * 16;
  const int bS = b * SEQ;
  const size_t hoff = (size_t)h * 64;
  const int niter = 2 * qx + 2;

  // persistent Q fragments (pre-scaled by 0.125*log2e via weight split)
  f16x8 qh[2], ql[2];
#pragma unroll
  for (int ks = 0; ks < 2; ks++) {
    const size_t base = (size_t)(bS + qw + q4) * D_MODEL + hoff + ks * 32 + g * 8;
    qh[ks] = *(const f16x8*)(Qhi + base);
    ql[ks] = *(const f16x8*)(Qlo + base);
  }

  f32x4 o[4] = {};
  float m_run = -INFINITY, l_run = 0.f;

  const int src_off = 8 * ((l & 7) ^ (l >> 3));
  const int rowloc = w * 8 + (l >> 3);

  auto stage = [&](int t) {
    const int kv0 = t * 64;
    char* kdst = smem + (t & 1) * 16384 + (w << 10);
    const size_t krow = (size_t)(bS + kv0 + rowloc) * D_MODEL + hoff + src_off;
    gload16(Khi + krow, kdst);
    gload16(Klo + krow, kdst + 8192);
    char* vdst = smem + 32768 + (t % 3) * 8192 + (w << 10);
    const size_t vrow = (hoff + rowloc) * (size_t)NROWS + bS + kv0 + src_off;
    gload16(VT + vrow, vdst);
  };

  f32x4 scur[4] = {};
  auto qkt = [&](int t) {
    const char* kb = smem + (t & 1) * 16384;
    __builtin_amdgcn_s_setprio(1);
#pragma unroll
    for (int ni = 0; ni < 4; ni++) {
      const int row = ni * 16 + q4;
      f32x4 acc = {};
#pragma unroll
      for (int ks = 0; ks < 2; ks++) {
        const int boff = row * 128 + 16 * ((ks * 4 + g) ^ (row & 7));
        f16x8 kh8 = *(const f16x8*)(kb + boff);
        f16x8 kl8 = *(const f16x8*)(kb + 8192 + boff);
        acc = MFMA16(kh8, qh[ks], acc, 0, 0, 0);
        acc = MFMA16(kh8, ql[ks], acc, 0, 0, 0);
        acc = MFMA16(kl8, qh[ks], acc, 0, 0, 0);
      }
      scur[ni] = acc;
    }
    __builtin_amdgcn_s_setprio(0);
  };

  // P^T redistribution constants
  const int idx_lo = (q4 + 32 * (g & 1)) * 4;
  const int idx_hi = idx_lo + 64;
  const bool upper = (l >= 32);

  // ---- prologue ----
  stage(0);
  stage(1);
  asm volatile("s_waitcnt vmcnt(3)" ::: "memory");
  __builtin_amdgcn_s_barrier();
  qkt(0);
  __builtin_amdgcn_s_barrier();

  for (int t = 0; t < niter; t++) {
    const bool hasn = (t + 1 < niter);
    const bool st2  = (t + 2 < niter);
    if (st2) stage(t + 2);

    const int kv0 = t * 64;
    if (kv0 <= qw + 15) {
      // ---- softmax(t) on scur ----
      const bool need_mask = (kv0 + 63) > qw;
      const int q_abs = qw + q4;
      float p[4][4];
      float pm = -INFINITY;
#pragma unroll
      for (int ni = 0; ni < 4; ni++)
#pragma unroll
        for (int j = 0; j < 4; j++) {
          float v = scur[ni][j];
          if (need_mask && (kv0 + ni*16 + 4*g + j) > q_abs) v = -INFINITY;
          p[ni][j] = v;
          pm = fmaxf(pm, v);
        }
      pm = fmaxf(pm, __shfl_xor(pm, 16));
      pm = fmaxf(pm, __shfl_xor(pm, 32));

      if (!__all(pm - m_run <= 8.0f)) {      // defer-max fast path
        const float mn = fmaxf(m_run, pm);
        const float sc = __builtin_amdgcn_exp2f(m_run - mn);
        m_run = mn;
        l_run *= sc;
#pragma unroll
        for (int nd = 0; nd < 4; nd++)
#pragma unroll
          for (int j = 0; j < 4; j++) o[nd][j] *= sc;
      }
      float ps = 0.f;
#pragma unroll
      for (int ni = 0; ni < 4; ni++)
#pragma unroll
        for (int j = 0; j < 4; j++) {
          const float e = __builtin_amdgcn_exp2f(p[ni][j] - m_run);
          p[ni][j] = e;
          ps += e;
        }
      ps += __shfl_xor(ps, 16);
      ps += __shfl_xor(ps, 32);
      l_run += ps;

      // ---- build P^T B-fragments ----
      f16x8 pa[2];
#pragma unroll
      for (int h2 = 0; h2 < 2; h2++) {
        const int pk0 = pkh2(p[2*h2][0],   p[2*h2][1]);
        const int pk1 = pkh2(p[2*h2][2],   p[2*h2][3]);
        const int pk2 = pkh2(p[2*h2+1][0], p[2*h2+1][1]);
        const int pk3 = pkh2(p[2*h2+1][2], p[2*h2+1][3]);
        const int b0l = __builtin_amdgcn_ds_bpermute(idx_lo, pk0);
        const int b2l = __builtin_amdgcn_ds_bpermute(idx_lo, pk2);
        const int b1l = __builtin_amdgcn_ds_bpermute(idx_lo, pk1);
        const int b3l = __builtin_amdgcn_ds_bpermute(idx_lo, pk3);
        const int b0h = __builtin_amdgcn_ds_bpermute(idx_hi, pk0);
        const int b2h = __builtin_amdgcn_ds_bpermute(idx_hi, pk2);
        const int b1h = __builtin_amdgcn_ds_bpermute(idx_hi, pk1);
        const int b3h = __builtin_amdgcn_ds_bpermute(idx_hi, pk3);
        union { int u[4]; f16x8 v; } pu;
        pu.u[0] = upper ? b2l : b0l;
        pu.u[1] = upper ? b3l : b1l;
        pu.u[2] = upper ? b2h : b0h;
        pu.u[3] = upper ? b3h : b1h;
        pa[h2] = pu.v;
      }

      // ---- PV(t): O^T += V^T P^T (V slot t%3, staged >=2 iters ago) ----
      const char* vb = smem + 32768 + (t % 3) * 8192;
      __builtin_amdgcn_s_setprio(1);
#pragma unroll
      for (int nd = 0; nd < 4; nd++) {
        const int d = nd * 16 + q4;
#pragma unroll
        for (int h2 = 0; h2 < 2; h2++) {
          f16x8 bv = *(const f16x8*)(vb + d * 128 + 16 * ((h2 * 4 + g) ^ (d & 7)));
          o[nd] = MFMA16(bv, pa[h2], o[nd], 0, 0, 0);
        }
      }
      __builtin_amdgcn_s_setprio(0);
    }

    if (hasn) {
      if (st2) asm volatile("s_waitcnt vmcnt(3)" ::: "memory");
      else     asm volatile("s_waitcnt vmcnt(0)" ::: "memory");
      __builtin_amdgcn_s_barrier();
      if (64 * (t + 1) <= qw + 15) qkt(t + 1);   // overwrites scur (dead)
      __builtin_amdgcn_s_barrier();
    }
  }

  // ---- epilogue: O^T[d][q] -> Out[q][d], 8B stores ----
  const float inv = 1.0f / l_run;
  const size_t rowb = (size_t)(bS + qw + q4) * D_MODEL + hoff;
#pragma unroll
  for (int nd = 0; nd < 4; nd++) {
    f16x4 v;
#pragma unroll
    for (int j = 0; j < 4; j++) v[j] = (f16)(o[nd][j] * inv);
    *reinterpret_cast<f16x4*>(Out + rowb + nd * 16 + 4 * g) = v;
  }
}

// ---------------- launcher ----------------
extern "C" void kernel_launch(void* const* d_in, const int* in_sizes, int n_in,
                              void* d_out, int out_size, void* d_ws, size_t ws_size,
                              hipStream_t stream) {
  const float* x  = (const float*)d_in[0];
  const float* pq = (const float*)d_in[1];
  const float* pk = (const float*)d_in[2];
  const float* pv = (const float*)d_in[3];
  const float* po = (const float*)d_in[4];
  float* out = (float*)d_out;

  char* ws = (char*)d_ws;
  size_t off = 0;
  auto alloc = [&](size_t elems) {
    f16* p = (f16*)(ws + off);
    off += ((elems * 2 + 255) & ~(size_t)255);
    return p;
  };
  f16* x_hi  = alloc((size_t)NROWS * D_MODEL);
  f16* x_lo  = alloc((size_t)NROWS * D_MODEL);
  f16* wq_hi = alloc((size_t)D_MODEL * D_MODEL);
  f16* wq_lo = alloc((size_t)D_MODEL * D_MODEL);
  f16* wk_hi = alloc((size_t)D_MODEL * D_MODEL);
  f16* wk_lo = alloc((size_t)D_MODEL * D_MODEL);
  f16* wv_h  = alloc((size_t)D_MODEL * D_MODEL);
  f16* wo_h  = alloc((size_t)D_MODEL * D_MODEL);
  f16* q_hi  = alloc((size_t)NROWS * D_MODEL);
  f16* q_lo  = alloc((size_t)NROWS * D_MODEL);
  f16* k_hi  = alloc((size_t)NROWS * D_MODEL);
  f16* k_lo  = alloc((size_t)NROWS * D_MODEL);
  f16* vt    = alloc((size_t)NROWS * D_MODEL);   // VT[m][b*SEQ+s]
  f16* ao    = alloc((size_t)NROWS * D_MODEL);

  const int n4x = NROWS * D_MODEL / 4;
  const int n4w = D_MODEL * D_MODEL / 4;
  const float qscale = 0.125f * 1.44269504088896f;
  split4_kernel<<<n4x/256, 256, 0, stream>>>(x, x_hi, x_lo, n4x, 1.0f);
  prep_w_kernel<<<n4w/256, 256, 0, stream>>>(pq, pk, pv, po,
                                             wq_hi, wq_lo, wk_hi, wk_lo, wv_h, wo_h,
                                             n4w, qscale);

  dim3 gg(D_MODEL/64, NROWS/128);  // (16, 32)
  gemm_nt<true,  true,  false, false><<<gg, 256, 0, stream>>>(x_hi, x_lo, wq_hi, wq_lo, q_hi, q_lo, nullptr, NROWS, D_MODEL, D_MODEL);
  gemm_nt<true,  true,  false, false><<<gg, 256, 0, stream>>>(x_hi, x_lo, wk_hi, wk_lo, k_hi, k_lo, nullptr, NROWS, D_MODEL, D_MODEL);
  // V projection with transposed output: VT[m][n] = sum_k wv[m][k] x[n][k]
  dim3 gv(NROWS/64, D_MODEL/128);  // (64, 8) -- col-chunked XCD swizzle
  gemm_nt<false, false, false, true><<<gv, 256, 0, stream>>>(wv_h, nullptr, x_hi, nullptr, vt, nullptr, nullptr, D_MODEL, NROWS, D_MODEL);

  attn_kernel<<<dim3(512), 512, 0, stream>>>(q_hi, q_lo, k_hi, k_lo, vt, ao);

  gemm_nt<false, false, true, false><<<gg, 256, 0, stream>>>(ao, nullptr, wo_h, nullptr, nullptr, nullptr, out, NROWS, D_MODEL, D_MODEL);
}

// Round 8
// 180.254 us; speedup vs baseline: 1.0342x; 1.0342x over previous
//
#include <hip/hip_runtime.h>
#include <stdint.h>

#define D_MODEL 1024
#define SEQ     2048
#define NHEAD   16
#define BATCH   2
#define NROWS   (BATCH*SEQ)   // 4096

typedef _Float16 f16;
typedef _Float16 f16x8 __attribute__((ext_vector_type(8)));
typedef _Float16 f16x4 __attribute__((ext_vector_type(4)));
typedef __fp16   h16x2 __attribute__((ext_vector_type(2)));
typedef float    f32x4 __attribute__((ext_vector_type(4)));

#define MFMA16 __builtin_amdgcn_mfma_f32_16x16x32_f16

__device__ __forceinline__ void gload16(const void* g, void* l) {
  __builtin_amdgcn_global_load_lds(
      (const __attribute__((address_space(1))) void*)g,
      (__attribute__((address_space(3))) void*)l, 16, 0, 0);
}

__device__ __forceinline__ int pkh2(float a, float b) {
  union { h16x2 h; int i; } u;
  u.h = __builtin_amdgcn_cvt_pkrtz(a, b);
  return u.i;
}

// ---------------- convert / split kernels ----------------
__global__ void split4_kernel(const float* __restrict__ in, f16* __restrict__ hi,
                              f16* __restrict__ lo, int n4, float scale) {
  int i = blockIdx.x * blockDim.x + threadIdx.x;
  if (i >= n4) return;
  float4 v = reinterpret_cast<const float4*>(in)[i];
  v.x *= scale; v.y *= scale; v.z *= scale; v.w *= scale;
  f16x4 h, l4;
  h[0] = (f16)v.x; h[1] = (f16)v.y; h[2] = (f16)v.z; h[3] = (f16)v.w;
  l4[0] = (f16)(v.x - (float)h[0]);
  l4[1] = (f16)(v.y - (float)h[1]);
  l4[2] = (f16)(v.z - (float)h[2]);
  l4[3] = (f16)(v.w - (float)h[3]);
  *reinterpret_cast<f16x4*>(hi + 4*(size_t)i) = h;
  *reinterpret_cast<f16x4*>(lo + 4*(size_t)i) = l4;
}

// fused weight prep: wq split (scaled), wk split, wv cvt, wo cvt — one pass
__global__ void prep_w_kernel(const float* __restrict__ pq, const float* __restrict__ pk,
                              const float* __restrict__ pv, const float* __restrict__ po,
                              f16* __restrict__ wq_hi, f16* __restrict__ wq_lo,
                              f16* __restrict__ wk_hi, f16* __restrict__ wk_lo,
                              f16* __restrict__ wv_h,  f16* __restrict__ wo_h,
                              int n4, float qscale) {
  int i = blockIdx.x * blockDim.x + threadIdx.x;
  if (i >= n4) return;
  {
    float4 v = reinterpret_cast<const float4*>(pq)[i];
    v.x *= qscale; v.y *= qscale; v.z *= qscale; v.w *= qscale;
    f16x4 h, l4;
    h[0] = (f16)v.x; h[1] = (f16)v.y; h[2] = (f16)v.z; h[3] = (f16)v.w;
    l4[0] = (f16)(v.x - (float)h[0]); l4[1] = (f16)(v.y - (float)h[1]);
    l4[2] = (f16)(v.z - (float)h[2]); l4[3] = (f16)(v.w - (float)h[3]);
    *reinterpret_cast<f16x4*>(wq_hi + 4*(size_t)i) = h;
    *reinterpret_cast<f16x4*>(wq_lo + 4*(size_t)i) = l4;
  }
  {
    float4 v = reinterpret_cast<const float4*>(pk)[i];
    f16x4 h, l4;
    h[0] = (f16)v.x; h[1] = (f16)v.y; h[2] = (f16)v.z; h[3] = (f16)v.w;
    l4[0] = (f16)(v.x - (float)h[0]); l4[1] = (f16)(v.y - (float)h[1]);
    l4[2] = (f16)(v.z - (float)h[2]); l4[3] = (f16)(v.w - (float)h[3]);
    *reinterpret_cast<f16x4*>(wk_hi + 4*(size_t)i) = h;
    *reinterpret_cast<f16x4*>(wk_lo + 4*(size_t)i) = l4;
  }
  {
    float4 v = reinterpret_cast<const float4*>(pv)[i];
    f16x4 h;
    h[0] = (f16)v.x; h[1] = (f16)v.y; h[2] = (f16)v.z; h[3] = (f16)v.w;
    *reinterpret_cast<f16x4*>(wv_h + 4*(size_t)i) = h;
  }
  {
    float4 v = reinterpret_cast<const float4*>(po)[i];
    f16x4 h;
    h[0] = (f16)v.x; h[1] = (f16)v.y; h[2] = (f16)v.z; h[3] = (f16)v.w;
    *reinterpret_cast<f16x4*>(wo_h + 4*(size_t)i) = h;
  }
}

// ---------------- GEMM: C[M,N] = A[M,K] · B[N,K]^T  (NT) ----------------
template<bool SPLIT_IN, bool SPLIT_OUT, bool F32_OUT, bool COLCHUNK>
__global__ __launch_bounds__(256, 2)
void gemm_nt(const f16* __restrict__ Ahi, const f16* __restrict__ Alo,
             const f16* __restrict__ Bhi, const f16* __restrict__ Blo,
             f16* __restrict__ Chi, f16* __restrict__ Clo, float* __restrict__ Cf,
             int M, int N, int K)
{
  constexpr int ALO_OFF = 8192;
  constexpr int B_OFF   = SPLIT_IN ? 16384 : 8192;
  constexpr int BLO_OFF = 20480;
  constexpr int STRIDE  = SPLIT_IN ? 24576 : 12288;
  __shared__ __align__(16) char smem[2 * STRIDE];

  const int tid = threadIdx.x;
  const int w = tid >> 6, l = tid & 63;
  const int wr = (w >> 1) * 64;
  const int wc = (w & 1) * 32;

  const int gx = gridDim.x, gy = gridDim.y;
  const int nwg = gx * gy;
  const int flat = blockIdx.y * gx + blockIdx.x;
  const int swz = (flat & 7) * (nwg >> 3) + (flat >> 3);
  const int bxn = COLCHUNK ? (swz / gy) : (swz % gx);
  const int byn = COLCHUNK ? (swz % gy) : (swz / gx);
  const int bm = byn * 128, bn = bxn * 64;

  f32x4 acc[4][2] = {};

  const int srow = tid >> 2;
  const int schunk = 8 * (((tid & 3) ^ ((srow >> 1) & 3)));

  auto stage = [&](int kt) {
    char* dst = smem + (kt & 1) * STRIDE;
    const int k0 = kt * 32;
    const f16* ga = Ahi + (size_t)(bm + srow) * K + k0 + schunk;
    gload16(ga,        dst + (w << 10));
    gload16(ga + 64*K, dst + 4096 + (w << 10));
    const f16* gb = Bhi + (size_t)(bn + srow) * K + k0 + schunk;
    gload16(gb,        dst + B_OFF + (w << 10));
    if (SPLIT_IN) {
      const f16* gal = Alo + (size_t)(bm + srow) * K + k0 + schunk;
      gload16(gal,        dst + ALO_OFF + (w << 10));
      gload16(gal + 64*K, dst + ALO_OFF + 4096 + (w << 10));
      const f16* gbl = Blo + (size_t)(bn + srow) * K + k0 + schunk;
      gload16(gbl,        dst + BLO_OFF + (w << 10));
    }
  };

  const int nkt = K >> 5;
  stage(0);

  for (int kt = 0; kt < nkt; kt++) {
    if (kt + 1 < nkt) {
      stage(kt + 1);
      if constexpr (SPLIT_IN) asm volatile("s_waitcnt vmcnt(6)" ::: "memory");
      else                    asm volatile("s_waitcnt vmcnt(3)" ::: "memory");
    } else {
      asm volatile("s_waitcnt vmcnt(0)" ::: "memory");
    }
    __builtin_amdgcn_s_barrier();

    const char* buf = smem + (kt & 1) * STRIDE;
    const int ar = (l & 15);
    const int ak = 16 * ((l >> 4) ^ ((ar >> 1) & 3));
    f16x8 a_hi[4], a_lo[4];
#pragma unroll
    for (int mi = 0; mi < 4; mi++) {
      a_hi[mi] = *(const f16x8*)(buf + (size_t)(wr + mi*16 + ar) * 64 + ak);
      if (SPLIT_IN)
        a_lo[mi] = *(const f16x8*)(buf + ALO_OFF + (size_t)(wr + mi*16 + ar) * 64 + ak);
    }
    __builtin_amdgcn_s_setprio(1);
#pragma unroll
    for (int ni = 0; ni < 2; ni++) {
      f16x8 b_hi = *(const f16x8*)(buf + B_OFF + (size_t)(wc + ni*16 + ar) * 64 + ak);
      f16x8 b_lo = {};
      if (SPLIT_IN)
        b_lo = *(const f16x8*)(buf + BLO_OFF + (size_t)(wc + ni*16 + ar) * 64 + ak);
#pragma unroll
      for (int mi = 0; mi < 4; mi++) {
        acc[mi][ni] = MFMA16(a_hi[mi], b_hi, acc[mi][ni], 0, 0, 0);
        if (SPLIT_IN) {
          acc[mi][ni] = MFMA16(a_hi[mi], b_lo, acc[mi][ni], 0, 0, 0);
          acc[mi][ni] = MFMA16(a_lo[mi], b_hi, acc[mi][ni], 0, 0, 0);
        }
      }
    }
    __builtin_amdgcn_s_setprio(0);
    __builtin_amdgcn_s_barrier();
  }

  const int crow0 = bm + wr + (l >> 4) * 4;
  const int ccol0 = bn + wc + (l & 15);
#pragma unroll
  for (int mi = 0; mi < 4; mi++) {
#pragma unroll
    for (int ni = 0; ni < 2; ni++) {
#pragma unroll
      for (int j = 0; j < 4; j++) {
        size_t idx = (size_t)(crow0 + mi*16 + j) * N + (ccol0 + ni*16);
        float v = acc[mi][ni][j];
        if (F32_OUT) {
          Cf[idx] = v;
        } else {
          f16 h = (f16)v;
          Chi[idx] = h;
          if (SPLIT_OUT) Clo[idx] = (f16)(v - (float)h);
        }
      }
    }
  }
}

// ---------------- flash attention v7 (causal, uniform-duration pair blocks) ----------
// Block = q-tile pair (c, 31-c), 64 rows each; waves 0-3 = group A, 4-7 = group B.
// KVBLK=32, ring of 4 x 12KB LDS slots (Khi|Klo|VT), staged by waves 0-5.
// Phase 1 (t=0..2c+1): both groups compute the same staged kv tile vs own rows.
// Transition: group A writes its finished output, reloads Q for B rows, resets.
// Phase 2 (pairs): group A takes even kv tiles, group B odd (2 tiles/iter);
// partial (m,l,o) merged via LDS at the end. Every block = exactly 33 iters ->
// 512 blocks land 2/CU and finish together (no causal tail).
__global__ __launch_bounds__(512, 4)
void attn_kernel(const f16* __restrict__ Qhi, const f16* __restrict__ Qlo,
                 const f16* __restrict__ Khi, const f16* __restrict__ Klo,
                 const f16* __restrict__ VT, f16* __restrict__ Out)
{
  __shared__ __align__(16) char smem[49152];   // 4 x 12KB ring (+ merge reuse)

  const int tid = threadIdx.x, w = tid >> 6, l = tid & 63;
  const int g = l >> 4, q4 = l & 15;
  const int wi = w & 3, grp = w >> 2;
  const int flat = blockIdx.x;
  const int xcd = flat & 7, slot = flat >> 3;
  const int bh = xcd * 4 + (slot >> 4);        // 4 heads resident per XCD
  const int c = slot & 15;
  const int b = bh >> 4, h = bh & 15;
  const int bS = b * SEQ;
  const size_t hoff = (size_t)h * 64;
  const int T  = 64 - 2 * c;                   // kv tiles needed by B
  const int P1 = 2 * c + 2;                    // phase-1 iterations
  const int P2 = 31 - 2 * c;                   // phase-2 pair-iterations

  int qw = (grp ? (31 - c) : c) * 64 + wi * 16;

  f16x8 qh[2], ql[2];
  auto loadQ = [&]() {
#pragma unroll
    for (int ks = 0; ks < 2; ks++) {
      const size_t base = (size_t)(bS + qw + q4) * D_MODEL + hoff + ks * 32 + g * 8;
      qh[ks] = *(const f16x8*)(Qhi + base);
      ql[ks] = *(const f16x8*)(Qlo + base);
    }
  };
  loadQ();

  f32x4 o[4] = {};
  float m_run = -INFINITY, l_run = 0.f;

  const int k_src = 8 * ((l & 7) ^ (l >> 3));          // K: chunk ^ (row&7)
  const int v_src = 8 * ((l & 3) ^ ((l >> 2) & 3));    // VT: chunk ^ (drow&3)

  auto stage = [&](int t) {
    const int kv0 = t * 32;
    char* sb = smem + (t & 3) * 12288;
    if (w < 4) {
      const f16* src = (w < 2) ? Khi : Klo;
      char* dstc = sb + ((w < 2) ? 0 : 4096);
      const int wi2 = w & 1;
#pragma unroll
      for (int gi = 0; gi < 2; gi++) {
        const int sub = 2 * wi2 + gi;                  // 0..3
        const int row = 8 * sub + (l >> 3);            // 0..31
        gload16(src + (size_t)(bS + kv0 + row) * D_MODEL + hoff + k_src,
                dstc + sub * 1024);
      }
    } else if (w < 6) {
      const int wi2 = w - 4;
#pragma unroll
      for (int gi = 0; gi < 2; gi++) {
        const int sub = 2 * wi2 + gi;                  // 0..3
        const int drow = 16 * sub + (l >> 2);          // 0..63
        gload16(VT + (hoff + drow) * (size_t)NROWS + bS + kv0 + v_src,
                sb + 8192 + sub * 1024);
      }
    }
  };

  // P^T redistribution constants
  const int idx_lo = (q4 + 32 * (g & 1)) * 4;
  const int idx_hi = idx_lo + 64;
  const bool upper = (l >= 32);

  auto compute = [&](int t) {
    const char* sb = smem + (t & 3) * 12288;
    const int kv0 = t * 32;

    // ---- S^T = K Q^T (split fp16, exp2 domain) ----
    f32x4 s[2] = {};
    __builtin_amdgcn_s_setprio(1);
#pragma unroll
    for (int ni = 0; ni < 2; ni++) {
      const int row = ni * 16 + q4;
#pragma unroll
      for (int ks = 0; ks < 2; ks++) {
        const int boff = row * 128 + 16 * ((ks * 4 + g) ^ (row & 7));
        f16x8 kh8 = *(const f16x8*)(sb + boff);
        f16x8 kl8 = *(const f16x8*)(sb + 4096 + boff);
        s[ni] = MFMA16(kh8, qh[ks], s[ni], 0, 0, 0);
        s[ni] = MFMA16(kh8, ql[ks], s[ni], 0, 0, 0);
        s[ni] = MFMA16(kl8, qh[ks], s[ni], 0, 0, 0);
      }
    }
    __builtin_amdgcn_s_setprio(0);

    // ---- causal mask + row max ----
    const bool need_mask = (kv0 + 31) > qw;
    const int q_abs = qw + q4;
    float p[2][4];
    float pm = -INFINITY;
#pragma unroll
    for (int ni = 0; ni < 2; ni++)
#pragma unroll
      for (int j = 0; j < 4; j++) {
        float v = s[ni][j];
        if (need_mask && (kv0 + ni * 16 + 4 * g + j) > q_abs) v = -INFINITY;
        p[ni][j] = v;
        pm = fmaxf(pm, v);
      }
    pm = fmaxf(pm, __shfl_xor(pm, 16));
    pm = fmaxf(pm, __shfl_xor(pm, 32));

    // ---- online softmax (exp2, defer-max) ----
    if (!__all(pm - m_run <= 8.0f)) {
      const float mn = fmaxf(m_run, pm);
      const float sc = __builtin_amdgcn_exp2f(m_run - mn);
      m_run = mn;
      l_run *= sc;
#pragma unroll
      for (int nd = 0; nd < 4; nd++)
#pragma unroll
        for (int j = 0; j < 4; j++) o[nd][j] *= sc;
    }
    float ps = 0.f;
#pragma unroll
    for (int ni = 0; ni < 2; ni++)
#pragma unroll
      for (int j = 0; j < 4; j++) {
        const float e = __builtin_amdgcn_exp2f(p[ni][j] - m_run);
        p[ni][j] = e;
        ps += e;
      }
    ps += __shfl_xor(ps, 16);
    ps += __shfl_xor(ps, 32);
    l_run += ps;

    // ---- build P^T B-fragment in-register ----
    const int pk0 = pkh2(p[0][0], p[0][1]);
    const int pk1 = pkh2(p[0][2], p[0][3]);
    const int pk2 = pkh2(p[1][0], p[1][1]);
    const int pk3 = pkh2(p[1][2], p[1][3]);
    const int b0l = __builtin_amdgcn_ds_bpermute(idx_lo, pk0);
    const int b2l = __builtin_amdgcn_ds_bpermute(idx_lo, pk2);
    const int b1l = __builtin_amdgcn_ds_bpermute(idx_lo, pk1);
    const int b3l = __builtin_amdgcn_ds_bpermute(idx_lo, pk3);
    const int b0h = __builtin_amdgcn_ds_bpermute(idx_hi, pk0);
    const int b2h = __builtin_amdgcn_ds_bpermute(idx_hi, pk2);
    const int b1h = __builtin_amdgcn_ds_bpermute(idx_hi, pk1);
    const int b3h = __builtin_amdgcn_ds_bpermute(idx_hi, pk3);
    union { int u[4]; f16x8 v; } pu;
    pu.u[0] = upper ? b2l : b0l;
    pu.u[1] = upper ? b3l : b1l;
    pu.u[2] = upper ? b2h : b0h;
    pu.u[3] = upper ? b3h : b1h;
    const f16x8 pa = pu.v;

    // ---- O^T += V^T P^T ----
    __builtin_amdgcn_s_setprio(1);
#pragma unroll
    for (int nd = 0; nd < 4; nd++) {
      const int d = nd * 16 + q4;
      f16x8 bv = *(const f16x8*)(sb + 8192 + d * 64 + 16 * (g ^ (d & 3)));
      o[nd] = MFMA16(bv, pa, o[nd], 0, 0, 0);
    }
    __builtin_amdgcn_s_setprio(0);
  };

  // ---- prologue ----
  stage(0);
  stage(1);

  // ---- phase 1: both groups, same tile ----
  for (int t = 0; t < P1; t++) {
    stage(t + 2);                       // always valid in phase 1
    asm volatile("s_waitcnt vmcnt(4)" ::: "memory");
    __builtin_amdgcn_s_barrier();
    compute(t);
    __builtin_amdgcn_s_barrier();
  }

  // ---- transition: group A writes output, switches to B rows ----
  if (grp == 0) {
    const float inv = 1.0f / l_run;
    const size_t rowb = (size_t)(bS + qw + q4) * D_MODEL + hoff;
#pragma unroll
    for (int nd = 0; nd < 4; nd++) {
      f16x4 v;
#pragma unroll
      for (int j = 0; j < 4; j++) v[j] = (f16)(o[nd][j] * inv);
      *reinterpret_cast<f16x4*>(Out + rowb + nd * 16 + 4 * g) = v;
    }
    qw = (31 - c) * 64 + wi * 16;
    loadQ();
#pragma unroll
    for (int nd = 0; nd < 4; nd++)
#pragma unroll
      for (int j = 0; j < 4; j++) o[nd][j] = 0.f;
    m_run = -INFINITY;
    l_run = 0.f;
  }

  // ---- phase 2: group A = even kv tiles, group B = odd ----
  for (int j = 0; j < P2; j++) {
    const int u = P1 + 2 * j;
    const bool st = (u + 3) < T;
    if (st) { stage(u + 2); stage(u + 3); }
    if (st) asm volatile("s_waitcnt vmcnt(4)" ::: "memory");
    else    asm volatile("s_waitcnt vmcnt(0)" ::: "memory");
    __builtin_amdgcn_s_barrier();
    compute(u + grp);
    __builtin_amdgcn_s_barrier();
  }

  // ---- merge group A's phase-2 partial into group B's state, write B ----
  if (grp == 0) {
    float* mb = (float*)smem + wi * 1152 + l * 18;
#pragma unroll
    for (int nd = 0; nd < 4; nd++)
#pragma unroll
      for (int j = 0; j < 4; j++) mb[nd * 4 + j] = o[nd][j];
    mb[16] = m_run;
    mb[17] = l_run;
  }
  __syncthreads();
  if (grp == 1) {
    const float* mb = (const float*)smem + wi * 1152 + l * 18;
    const float m2 = mb[16], l2 = mb[17];
    const float mm = fmaxf(m_run, m2);
    const float a1 = __builtin_amdgcn_exp2f(m_run - mm);
    const float a2 = __builtin_amdgcn_exp2f(m2 - mm);
    const float inv = 1.0f / (l_run * a1 + l2 * a2);
    const size_t rowb = (size_t)(bS + qw + q4) * D_MODEL + hoff;
#pragma unroll
    for (int nd = 0; nd < 4; nd++) {
      f16x4 v;
#pragma unroll
      for (int j = 0; j < 4; j++)
        v[j] = (f16)((o[nd][j] * a1 + mb[nd * 4 + j] * a2) * inv);
      *reinterpret_cast<f16x4*>(Out + rowb + nd * 16 + 4 * g) = v;
    }
  }
}

// ---------------- launcher ----------------
extern "C" void kernel_launch(void* const* d_in, const int* in_sizes, int n_in,
                              void* d_out, int out_size, void* d_ws, size_t ws_size,
                              hipStream_t stream) {
  const float* x  = (const float*)d_in[0];
  const float* pq = (const float*)d_in[1];
  const float* pk = (const float*)d_in[2];
  const float* pv = (const float*)d_in[3];
  const float* po = (const float*)d_in[4];
  float* out = (float*)d_out;

  char* ws = (char*)d_ws;
  size_t off = 0;
  auto alloc = [&](size_t elems) {
    f16* p = (f16*)(ws + off);
    off += ((elems * 2 + 255) & ~(size_t)255);
    return p;
  };
  f16* x_hi  = alloc((size_t)NROWS * D_MODEL);
  f16* x_lo  = alloc((size_t)NROWS * D_MODEL);
  f16* wq_hi = alloc((size_t)D_MODEL * D_MODEL);
  f16* wq_lo = alloc((size_t)D_MODEL * D_MODEL);
  f16* wk_hi = alloc((size_t)D_MODEL * D_MODEL);
  f16* wk_lo = alloc((size_t)D_MODEL * D_MODEL);
  f16* wv_h  = alloc((size_t)D_MODEL * D_MODEL);
  f16* wo_h  = alloc((size_t)D_MODEL * D_MODEL);
  f16* q_hi  = alloc((size_t)NROWS * D_MODEL);
  f16* q_lo  = alloc((size_t)NROWS * D_MODEL);
  f16* k_hi  = alloc((size_t)NROWS * D_MODEL);
  f16* k_lo  = alloc((size_t)NROWS * D_MODEL);
  f16* vt    = alloc((size_t)NROWS * D_MODEL);   // VT[m][b*SEQ+s]
  f16* ao    = alloc((size_t)NROWS * D_MODEL);

  const int n4x = NROWS * D_MODEL / 4;
  const int n4w = D_MODEL * D_MODEL / 4;
  const float qscale = 0.125f * 1.44269504088896f;
  split4_kernel<<<n4x/256, 256, 0, stream>>>(x, x_hi, x_lo, n4x, 1.0f);
  prep_w_kernel<<<n4w/256, 256, 0, stream>>>(pq, pk, pv, po,
                                             wq_hi, wq_lo, wk_hi, wk_lo, wv_h, wo_h,
                                             n4w, qscale);

  dim3 gg(D_MODEL/64, NROWS/128);  // (16, 32)
  gemm_nt<true,  true,  false, false><<<gg, 256, 0, stream>>>(x_hi, x_lo, wq_hi, wq_lo, q_hi, q_lo, nullptr, NROWS, D_MODEL, D_MODEL);
  gemm_nt<true,  true,  false, false><<<gg, 256, 0, stream>>>(x_hi, x_lo, wk_hi, wk_lo, k_hi, k_lo, nullptr, NROWS, D_MODEL, D_MODEL);
  // V projection with transposed output: VT[m][n] = sum_k wv[m][k] x[n][k]
  dim3 gv(NROWS/64, D_MODEL/128);  // (64, 8) -- col-chunked XCD swizzle
  gemm_nt<false, false, false, true><<<gv, 256, 0, stream>>>(wv_h, nullptr, x_hi, nullptr, vt, nullptr, nullptr, D_MODEL, NROWS, D_MODEL);

  attn_kernel<<<dim3(512), 512, 0, stream>>>(q_hi, q_lo, k_hi, k_lo, vt, ao);

  gemm_nt<false, false, true, false><<<gg, 256, 0, stream>>>(ao, nullptr, wo_h, nullptr, nullptr, nullptr, out, NROWS, D_MODEL, D_MODEL);
}

// Round 9
// 166.210 us; speedup vs baseline: 1.1216x; 1.0845x over previous
//
#include <hip/hip_runtime.h>
#include <stdint.h>

#define D_MODEL 1024
#define SEQ     2048
#define NHEAD   16
#define BATCH   2
#define NROWS   (BATCH*SEQ)   // 4096

typedef _Float16 f16;
typedef _Float16 f16x8 __attribute__((ext_vector_type(8)));
typedef _Float16 f16x4 __attribute__((ext_vector_type(4)));
typedef __fp16   h16x2 __attribute__((ext_vector_type(2)));
typedef float    f32x4 __attribute__((ext_vector_type(4)));

#define MFMA16 __builtin_amdgcn_mfma_f32_16x16x32_f16

__device__ __forceinline__ void gload16(const void* g, void* l) {
  __builtin_amdgcn_global_load_lds(
      (const __attribute__((address_space(1))) void*)g,
      (__attribute__((address_space(3))) void*)l, 16, 0, 0);
}

__device__ __forceinline__ int pkh2(float a, float b) {
  union { h16x2 h; int i; } u;
  u.h = __builtin_amdgcn_cvt_pkrtz(a, b);
  return u.i;
}

// ---------------- convert / split kernels ----------------
__global__ void split4_kernel(const float* __restrict__ in, f16* __restrict__ hi,
                              f16* __restrict__ lo, int n4, float scale) {
  int i = blockIdx.x * blockDim.x + threadIdx.x;
  if (i >= n4) return;
  float4 v = reinterpret_cast<const float4*>(in)[i];
  v.x *= scale; v.y *= scale; v.z *= scale; v.w *= scale;
  f16x4 h, l4;
  h[0] = (f16)v.x; h[1] = (f16)v.y; h[2] = (f16)v.z; h[3] = (f16)v.w;
  l4[0] = (f16)(v.x - (float)h[0]);
  l4[1] = (f16)(v.y - (float)h[1]);
  l4[2] = (f16)(v.z - (float)h[2]);
  l4[3] = (f16)(v.w - (float)h[3]);
  *reinterpret_cast<f16x4*>(hi + 4*(size_t)i) = h;
  *reinterpret_cast<f16x4*>(lo + 4*(size_t)i) = l4;
}

// fused weight prep: wq split (scaled), wk split, wv cvt, wo cvt — one pass
__global__ void prep_w_kernel(const float* __restrict__ pq, const float* __restrict__ pk,
                              const float* __restrict__ pv, const float* __restrict__ po,
                              f16* __restrict__ wq_hi, f16* __restrict__ wq_lo,
                              f16* __restrict__ wk_hi, f16* __restrict__ wk_lo,
                              f16* __restrict__ wv_h,  f16* __restrict__ wo_h,
                              int n4, float qscale) {
  int i = blockIdx.x * blockDim.x + threadIdx.x;
  if (i >= n4) return;
  {
    float4 v = reinterpret_cast<const float4*>(pq)[i];
    v.x *= qscale; v.y *= qscale; v.z *= qscale; v.w *= qscale;
    f16x4 h, l4;
    h[0] = (f16)v.x; h[1] = (f16)v.y; h[2] = (f16)v.z; h[3] = (f16)v.w;
    l4[0] = (f16)(v.x - (float)h[0]); l4[1] = (f16)(v.y - (float)h[1]);
    l4[2] = (f16)(v.z - (float)h[2]); l4[3] = (f16)(v.w - (float)h[3]);
    *reinterpret_cast<f16x4*>(wq_hi + 4*(size_t)i) = h;
    *reinterpret_cast<f16x4*>(wq_lo + 4*(size_t)i) = l4;
  }
  {
    float4 v = reinterpret_cast<const float4*>(pk)[i];
    f16x4 h, l4;
    h[0] = (f16)v.x; h[1] = (f16)v.y; h[2] = (f16)v.z; h[3] = (f16)v.w;
    l4[0] = (f16)(v.x - (float)h[0]); l4[1] = (f16)(v.y - (float)h[1]);
    l4[2] = (f16)(v.z - (float)h[2]); l4[3] = (f16)(v.w - (float)h[3]);
    *reinterpret_cast<f16x4*>(wk_hi + 4*(size_t)i) = h;
    *reinterpret_cast<f16x4*>(wk_lo + 4*(size_t)i) = l4;
  }
  {
    float4 v = reinterpret_cast<const float4*>(pv)[i];
    f16x4 h;
    h[0] = (f16)v.x; h[1] = (f16)v.y; h[2] = (f16)v.z; h[3] = (f16)v.w;
    *reinterpret_cast<f16x4*>(wv_h + 4*(size_t)i) = h;
  }
  {
    float4 v = reinterpret_cast<const float4*>(po)[i];
    f16x4 h;
    h[0] = (f16)v.x; h[1] = (f16)v.y; h[2] = (f16)v.z; h[3] = (f16)v.w;
    *reinterpret_cast<f16x4*>(wo_h + 4*(size_t)i) = h;
  }
}

// ---------------- GEMM: C[M,N] = A[M,K] · B[N,K]^T  (NT, plain fp16) -------------
template<bool F32_OUT, bool COLCHUNK>
__global__ __launch_bounds__(256, 2)
void gemm_nt(const f16* __restrict__ Ahi,
             const f16* __restrict__ Bhi,
             f16* __restrict__ Chi, float* __restrict__ Cf,
             int M, int N, int K)
{
  constexpr int B_OFF  = 8192;
  constexpr int STRIDE = 12288;
  __shared__ __align__(16) char smem[2 * STRIDE];

  const int tid = threadIdx.x;
  const int w = tid >> 6, l = tid & 63;
  const int wr = (w >> 1) * 64;
  const int wc = (w & 1) * 32;

  const int gx = gridDim.x, gy = gridDim.y;
  const int nwg = gx * gy;
  const int flat = blockIdx.y * gx + blockIdx.x;
  const int swz = (flat & 7) * (nwg >> 3) + (flat >> 3);
  const int bxn = COLCHUNK ? (swz / gy) : (swz % gx);
  const int byn = COLCHUNK ? (swz % gy) : (swz / gx);
  const int bm = byn * 128, bn = bxn * 64;

  f32x4 acc[4][2] = {};

  const int srow = tid >> 2;
  const int schunk = 8 * (((tid & 3) ^ ((srow >> 1) & 3)));

  auto stage = [&](int kt) {
    char* dst = smem + (kt & 1) * STRIDE;
    const int k0 = kt * 32;
    const f16* ga = Ahi + (size_t)(bm + srow) * K + k0 + schunk;
    gload16(ga,        dst + (w << 10));
    gload16(ga + 64*K, dst + 4096 + (w << 10));
    const f16* gb = Bhi + (size_t)(bn + srow) * K + k0 + schunk;
    gload16(gb,        dst + B_OFF + (w << 10));
  };

  const int nkt = K >> 5;
  stage(0);

  for (int kt = 0; kt < nkt; kt++) {
    if (kt + 1 < nkt) {
      stage(kt + 1);
      asm volatile("s_waitcnt vmcnt(3)" ::: "memory");
    } else {
      asm volatile("s_waitcnt vmcnt(0)" ::: "memory");
    }
    __builtin_amdgcn_s_barrier();

    const char* buf = smem + (kt & 1) * STRIDE;
    const int ar = (l & 15);
    const int ak = 16 * ((l >> 4) ^ ((ar >> 1) & 3));
    f16x8 a_hi[4];
#pragma unroll
    for (int mi = 0; mi < 4; mi++)
      a_hi[mi] = *(const f16x8*)(buf + (size_t)(wr + mi*16 + ar) * 64 + ak);
    __builtin_amdgcn_s_setprio(1);
#pragma unroll
    for (int ni = 0; ni < 2; ni++) {
      f16x8 b_hi = *(const f16x8*)(buf + B_OFF + (size_t)(wc + ni*16 + ar) * 64 + ak);
#pragma unroll
      for (int mi = 0; mi < 4; mi++)
        acc[mi][ni] = MFMA16(a_hi[mi], b_hi, acc[mi][ni], 0, 0, 0);
    }
    __builtin_amdgcn_s_setprio(0);
    __builtin_amdgcn_s_barrier();
  }

  const int crow0 = bm + wr + (l >> 4) * 4;
  const int ccol0 = bn + wc + (l & 15);
#pragma unroll
  for (int mi = 0; mi < 4; mi++) {
#pragma unroll
    for (int ni = 0; ni < 2; ni++) {
#pragma unroll
      for (int j = 0; j < 4; j++) {
        size_t idx = (size_t)(crow0 + mi*16 + j) * N + (ccol0 + ni*16);
        float v = acc[mi][ni][j];
        if (F32_OUT) Cf[idx] = v;
        else         Chi[idx] = (f16)v;
      }
    }
  }
}

// ---------------- fused Q+K projection GEMM (split fp16 x split fp16) -------------
// A = x (hi/lo) [4096 x 1024]; Bq = wq (hi/lo), Bk = wk (hi/lo) [1024 x 1024].
// Tile 128x64, BK=32, double-buffered (2x32KB LDS), counted vmcnt(8).
// A fragments amortize over BOTH Q and K MFMAs (16 ds_reads / 48 MFMA per
// wave-K-step -> MFMA-bound, vs 10/24 in the separate kernels).
__global__ __launch_bounds__(256, 2)
void gemm_qk(const f16* __restrict__ Ahi, const f16* __restrict__ Alo,
             const f16* __restrict__ Bqh, const f16* __restrict__ Bql,
             const f16* __restrict__ Bkh, const f16* __restrict__ Bkl,
             f16* __restrict__ Qh, f16* __restrict__ Qlo2,
             f16* __restrict__ Kh, f16* __restrict__ Klo2)
{
  constexpr int N = D_MODEL, K = D_MODEL;
  constexpr int STRIDE = 32768;
  __shared__ __align__(16) char smem[2 * STRIDE];
  // per buffer: Ahi 0 | Alo 8192 | Bqh 16384 | Bql 20480 | Bkh 24576 | Bkl 28672

  const int tid = threadIdx.x;
  const int w = tid >> 6, l = tid & 63;
  const int wr = (w >> 1) * 64;
  const int wc = (w & 1) * 32;

  const int flat = blockIdx.y * 16 + blockIdx.x;           // grid (16, 32)
  const int swz = (flat & 7) * 64 + (flat >> 3);           // XCD-chunked
  const int bm = (swz / 16) * 128, bn = (swz % 16) * 64;

  f32x4 accQ[4][2] = {}, accK[4][2] = {};

  const int srow = tid >> 2;
  const int schunk = 8 * (((tid & 3) ^ ((srow >> 1) & 3)));

  auto stage = [&](int kt) {
    char* dst = smem + (kt & 1) * STRIDE;
    const int k0 = kt * 32;
    const f16* ga = Ahi + (size_t)(bm + srow) * K + k0 + schunk;
    gload16(ga,        dst + (w << 10));
    gload16(ga + 64*K, dst + 4096 + (w << 10));
    const f16* gal = Alo + (size_t)(bm + srow) * K + k0 + schunk;
    gload16(gal,        dst + 8192 + (w << 10));
    gload16(gal + 64*K, dst + 12288 + (w << 10));
    const size_t bo = (size_t)(bn + srow) * K + k0 + schunk;
    gload16(Bqh + bo, dst + 16384 + (w << 10));
    gload16(Bql + bo, dst + 20480 + (w << 10));
    gload16(Bkh + bo, dst + 24576 + (w << 10));
    gload16(Bkl + bo, dst + 28672 + (w << 10));
  };

  const int nkt = K >> 5;   // 32
  stage(0);

  for (int kt = 0; kt < nkt; kt++) {
    if (kt + 1 < nkt) {
      stage(kt + 1);
      asm volatile("s_waitcnt vmcnt(8)" ::: "memory");
    } else {
      asm volatile("s_waitcnt vmcnt(0)" ::: "memory");
    }
    __builtin_amdgcn_s_barrier();

    const char* buf = smem + (kt & 1) * STRIDE;
    const int ar = (l & 15);
    const int ak = 16 * ((l >> 4) ^ ((ar >> 1) & 3));
    f16x8 a_hi[4], a_lo[4];
#pragma unroll
    for (int mi = 0; mi < 4; mi++) {
      a_hi[mi] = *(const f16x8*)(buf + (size_t)(wr + mi*16 + ar) * 64 + ak);
      a_lo[mi] = *(const f16x8*)(buf + 8192 + (size_t)(wr + mi*16 + ar) * 64 + ak);
    }
    __builtin_amdgcn_s_setprio(1);
#pragma unroll
    for (int ni = 0; ni < 2; ni++) {
      const int bo = (wc + ni*16 + ar) * 64 + ak;
      f16x8 bqh = *(const f16x8*)(buf + 16384 + bo);
      f16x8 bql = *(const f16x8*)(buf + 20480 + bo);
      f16x8 bkh = *(const f16x8*)(buf + 24576 + bo);
      f16x8 bkl = *(const f16x8*)(buf + 28672 + bo);
#pragma unroll
      for (int mi = 0; mi < 4; mi++) {
        accQ[mi][ni] = MFMA16(a_hi[mi], bqh, accQ[mi][ni], 0, 0, 0);
        accQ[mi][ni] = MFMA16(a_hi[mi], bql, accQ[mi][ni], 0, 0, 0);
        accQ[mi][ni] = MFMA16(a_lo[mi], bqh, accQ[mi][ni], 0, 0, 0);
        accK[mi][ni] = MFMA16(a_hi[mi], bkh, accK[mi][ni], 0, 0, 0);
        accK[mi][ni] = MFMA16(a_hi[mi], bkl, accK[mi][ni], 0, 0, 0);
        accK[mi][ni] = MFMA16(a_lo[mi], bkh, accK[mi][ni], 0, 0, 0);
      }
    }
    __builtin_amdgcn_s_setprio(0);
    __builtin_amdgcn_s_barrier();
  }

  const int crow0 = bm + wr + (l >> 4) * 4;
  const int ccol0 = bn + wc + (l & 15);
#pragma unroll
  for (int mi = 0; mi < 4; mi++) {
#pragma unroll
    for (int ni = 0; ni < 2; ni++) {
#pragma unroll
      for (int j = 0; j < 4; j++) {
        size_t idx = (size_t)(crow0 + mi*16 + j) * N + (ccol0 + ni*16);
        float qv = accQ[mi][ni][j];
        f16 qh = (f16)qv;
        Qh[idx] = qh;  Qlo2[idx] = (f16)(qv - (float)qh);
        float kv = accK[mi][ni][j];
        f16 kh = (f16)kv;
        Kh[idx] = kh;  Klo2[idx] = (f16)(kv - (float)kh);
      }
    }
  }
}

// ---------------- flash attention v7 (causal, uniform-duration pair blocks) ----------
// (unchanged from round 8 — isolating the GEMM change)
__global__ __launch_bounds__(512, 4)
void attn_kernel(const f16* __restrict__ Qhi, const f16* __restrict__ Qlo,
                 const f16* __restrict__ Khi, const f16* __restrict__ Klo,
                 const f16* __restrict__ VT, f16* __restrict__ Out)
{
  __shared__ __align__(16) char smem[49152];   // 4 x 12KB ring (+ merge reuse)

  const int tid = threadIdx.x, w = tid >> 6, l = tid & 63;
  const int g = l >> 4, q4 = l & 15;
  const int wi = w & 3, grp = w >> 2;
  const int flat = blockIdx.x;
  const int xcd = flat & 7, slot = flat >> 3;
  const int bh = xcd * 4 + (slot >> 4);        // 4 heads resident per XCD
  const int c = slot & 15;
  const int b = bh >> 4, h = bh & 15;
  const int bS = b * SEQ;
  const size_t hoff = (size_t)h * 64;
  const int T  = 64 - 2 * c;                   // kv tiles needed by B
  const int P1 = 2 * c + 2;                    // phase-1 iterations
  const int P2 = 31 - 2 * c;                   // phase-2 pair-iterations

  int qw = (grp ? (31 - c) : c) * 64 + wi * 16;

  f16x8 qh[2], ql[2];
  auto loadQ = [&]() {
#pragma unroll
    for (int ks = 0; ks < 2; ks++) {
      const size_t base = (size_t)(bS + qw + q4) * D_MODEL + hoff + ks * 32 + g * 8;
      qh[ks] = *(const f16x8*)(Qhi + base);
      ql[ks] = *(const f16x8*)(Qlo + base);
    }
  };
  loadQ();

  f32x4 o[4] = {};
  float m_run = -INFINITY, l_run = 0.f;

  const int k_src = 8 * ((l & 7) ^ (l >> 3));          // K: chunk ^ (row&7)
  const int v_src = 8 * ((l & 3) ^ ((l >> 2) & 3));    // VT: chunk ^ (drow&3)

  auto stage = [&](int t) {
    const int kv0 = t * 32;
    char* sb = smem + (t & 3) * 12288;
    if (w < 4) {
      const f16* src = (w < 2) ? Khi : Klo;
      char* dstc = sb + ((w < 2) ? 0 : 4096);
      const int wi2 = w & 1;
#pragma unroll
      for (int gi = 0; gi < 2; gi++) {
        const int sub = 2 * wi2 + gi;                  // 0..3
        const int row = 8 * sub + (l >> 3);            // 0..31
        gload16(src + (size_t)(bS + kv0 + row) * D_MODEL + hoff + k_src,
                dstc + sub * 1024);
      }
    } else if (w < 6) {
      const int wi2 = w - 4;
#pragma unroll
      for (int gi = 0; gi < 2; gi++) {
        const int sub = 2 * wi2 + gi;                  // 0..3
        const int drow = 16 * sub + (l >> 2);          // 0..63
        gload16(VT + (hoff + drow) * (size_t)NROWS + bS + kv0 + v_src,
                sb + 8192 + sub * 1024);
      }
    }
  };

  // P^T redistribution constants
  const int idx_lo = (q4 + 32 * (g & 1)) * 4;
  const int idx_hi = idx_lo + 64;
  const bool upper = (l >= 32);

  auto compute = [&](int t) {
    const char* sb = smem + (t & 3) * 12288;
    const int kv0 = t * 32;

    // ---- S^T = K Q^T (split fp16, exp2 domain) ----
    f32x4 s[2] = {};
    __builtin_amdgcn_s_setprio(1);
#pragma unroll
    for (int ni = 0; ni < 2; ni++) {
      const int row = ni * 16 + q4;
#pragma unroll
      for (int ks = 0; ks < 2; ks++) {
        const int boff = row * 128 + 16 * ((ks * 4 + g) ^ (row & 7));
        f16x8 kh8 = *(const f16x8*)(sb + boff);
        f16x8 kl8 = *(const f16x8*)(sb + 4096 + boff);
        s[ni] = MFMA16(kh8, qh[ks], s[ni], 0, 0, 0);
        s[ni] = MFMA16(kh8, ql[ks], s[ni], 0, 0, 0);
        s[ni] = MFMA16(kl8, qh[ks], s[ni], 0, 0, 0);
      }
    }
    __builtin_amdgcn_s_setprio(0);

    // ---- causal mask + row max ----
    const bool need_mask = (kv0 + 31) > qw;
    const int q_abs = qw + q4;
    float p[2][4];
    float pm = -INFINITY;
#pragma unroll
    for (int ni = 0; ni < 2; ni++)
#pragma unroll
      for (int j = 0; j < 4; j++) {
        float v = s[ni][j];
        if (need_mask && (kv0 + ni * 16 + 4 * g + j) > q_abs) v = -INFINITY;
        p[ni][j] = v;
        pm = fmaxf(pm, v);
      }
    pm = fmaxf(pm, __shfl_xor(pm, 16));
    pm = fmaxf(pm, __shfl_xor(pm, 32));

    // ---- online softmax (exp2, defer-max) ----
    if (!__all(pm - m_run <= 8.0f)) {
      const float mn = fmaxf(m_run, pm);
      const float sc = __builtin_amdgcn_exp2f(m_run - mn);
      m_run = mn;
      l_run *= sc;
#pragma unroll
      for (int nd = 0; nd < 4; nd++)
#pragma unroll
        for (int j = 0; j < 4; j++) o[nd][j] *= sc;
    }
    float ps = 0.f;
#pragma unroll
    for (int ni = 0; ni < 2; ni++)
#pragma unroll
      for (int j = 0; j < 4; j++) {
        const float e = __builtin_amdgcn_exp2f(p[ni][j] - m_run);
        p[ni][j] = e;
        ps += e;
      }
    ps += __shfl_xor(ps, 16);
    ps += __shfl_xor(ps, 32);
    l_run += ps;

    // ---- build P^T B-fragment in-register ----
    const int pk0 = pkh2(p[0][0], p[0][1]);
    const int pk1 = pkh2(p[0][2], p[0][3]);
    const int pk2 = pkh2(p[1][0], p[1][1]);
    const int pk3 = pkh2(p[1][2], p[1][3]);
    const int b0l = __builtin_amdgcn_ds_bpermute(idx_lo, pk0);
    const int b2l = __builtin_amdgcn_ds_bpermute(idx_lo, pk2);
    const int b1l = __builtin_amdgcn_ds_bpermute(idx_lo, pk1);
    const int b3l = __builtin_amdgcn_ds_bpermute(idx_lo, pk3);
    const int b0h = __builtin_amdgcn_ds_bpermute(idx_hi, pk0);
    const int b2h = __builtin_amdgcn_ds_bpermute(idx_hi, pk2);
    const int b1h = __builtin_amdgcn_ds_bpermute(idx_hi, pk1);
    const int b3h = __builtin_amdgcn_ds_bpermute(idx_hi, pk3);
    union { int u[4]; f16x8 v; } pu;
    pu.u[0] = upper ? b2l : b0l;
    pu.u[1] = upper ? b3l : b1l;
    pu.u[2] = upper ? b2h : b0h;
    pu.u[3] = upper ? b3h : b1h;
    const f16x8 pa = pu.v;

    // ---- O^T += V^T P^T ----
    __builtin_amdgcn_s_setprio(1);
#pragma unroll
    for (int nd = 0; nd < 4; nd++) {
      const int d = nd * 16 + q4;
      f16x8 bv = *(const f16x8*)(sb + 8192 + d * 64 + 16 * (g ^ (d & 3)));
      o[nd] = MFMA16(bv, pa, o[nd], 0, 0, 0);
    }
    __builtin_amdgcn_s_setprio(0);
  };

  // ---- prologue ----
  stage(0);
  stage(1);

  // ---- phase 1: both groups, same tile ----
  for (int t = 0; t < P1; t++) {
    stage(t + 2);                       // always valid in phase 1
    asm volatile("s_waitcnt vmcnt(4)" ::: "memory");
    __builtin_amdgcn_s_barrier();
    compute(t);
    __builtin_amdgcn_s_barrier();
  }

  // ---- transition: group A writes output, switches to B rows ----
  if (grp == 0) {
    const float inv = 1.0f / l_run;
    const size_t rowb = (size_t)(bS + qw + q4) * D_MODEL + hoff;
#pragma unroll
    for (int nd = 0; nd < 4; nd++) {
      f16x4 v;
#pragma unroll
      for (int j = 0; j < 4; j++) v[j] = (f16)(o[nd][j] * inv);
      *reinterpret_cast<f16x4*>(Out + rowb + nd * 16 + 4 * g) = v;
    }
    qw = (31 - c) * 64 + wi * 16;
    loadQ();
#pragma unroll
    for (int nd = 0; nd < 4; nd++)
#pragma unroll
      for (int j = 0; j < 4; j++) o[nd][j] = 0.f;
    m_run = -INFINITY;
    l_run = 0.f;
  }

  // ---- phase 2: group A = even kv tiles, group B = odd ----
  for (int j = 0; j < P2; j++) {
    const int u = P1 + 2 * j;
    const bool st = (u + 3) < T;
    if (st) { stage(u + 2); stage(u + 3); }
    if (st) asm volatile("s_waitcnt vmcnt(4)" ::: "memory");
    else    asm volatile("s_waitcnt vmcnt(0)" ::: "memory");
    __builtin_amdgcn_s_barrier();
    compute(u + grp);
    __builtin_amdgcn_s_barrier();
  }

  // ---- merge group A's phase-2 partial into group B's state, write B ----
  if (grp == 0) {
    float* mb = (float*)smem + wi * 1152 + l * 18;
#pragma unroll
    for (int nd = 0; nd < 4; nd++)
#pragma unroll
      for (int j = 0; j < 4; j++) mb[nd * 4 + j] = o[nd][j];
    mb[16] = m_run;
    mb[17] = l_run;
  }
  __syncthreads();
  if (grp == 1) {
    const float* mb = (const float*)smem + wi * 1152 + l * 18;
    const float m2 = mb[16], l2 = mb[17];
    const float mm = fmaxf(m_run, m2);
    const float a1 = __builtin_amdgcn_exp2f(m_run - mm);
    const float a2 = __builtin_amdgcn_exp2f(m2 - mm);
    const float inv = 1.0f / (l_run * a1 + l2 * a2);
    const size_t rowb = (size_t)(bS + qw + q4) * D_MODEL + hoff;
#pragma unroll
    for (int nd = 0; nd < 4; nd++) {
      f16x4 v;
#pragma unroll
      for (int j = 0; j < 4; j++)
        v[j] = (f16)((o[nd][j] * a1 + mb[nd * 4 + j] * a2) * inv);
      *reinterpret_cast<f16x4*>(Out + rowb + nd * 16 + 4 * g) = v;
    }
  }
}

// ---------------- launcher ----------------
extern "C" void kernel_launch(void* const* d_in, const int* in_sizes, int n_in,
                              void* d_out, int out_size, void* d_ws, size_t ws_size,
                              hipStream_t stream) {
  const float* x  = (const float*)d_in[0];
  const float* pq = (const float*)d_in[1];
  const float* pk = (const float*)d_in[2];
  const float* pv = (const float*)d_in[3];
  const float* po = (const float*)d_in[4];
  float* out = (float*)d_out;

  char* ws = (char*)d_ws;
  size_t off = 0;
  auto alloc = [&](size_t elems) {
    f16* p = (f16*)(ws + off);
    off += ((elems * 2 + 255) & ~(size_t)255);
    return p;
  };
  f16* x_hi  = alloc((size_t)NROWS * D_MODEL);
  f16* x_lo  = alloc((size_t)NROWS * D_MODEL);
  f16* wq_hi = alloc((size_t)D_MODEL * D_MODEL);
  f16* wq_lo = alloc((size_t)D_MODEL * D_MODEL);
  f16* wk_hi = alloc((size_t)D_MODEL * D_MODEL);
  f16* wk_lo = alloc((size_t)D_MODEL * D_MODEL);
  f16* wv_h  = alloc((size_t)D_MODEL * D_MODEL);
  f16* wo_h  = alloc((size_t)D_MODEL * D_MODEL);
  f16* q_hi  = alloc((size_t)NROWS * D_MODEL);
  f16* q_lo  = alloc((size_t)NROWS * D_MODEL);
  f16* k_hi  = alloc((size_t)NROWS * D_MODEL);
  f16* k_lo  = alloc((size_t)NROWS * D_MODEL);
  f16* vt    = alloc((size_t)NROWS * D_MODEL);   // VT[m][b*SEQ+s]
  f16* ao    = alloc((size_t)NROWS * D_MODEL);

  const int n4x = NROWS * D_MODEL / 4;
  const int n4w = D_MODEL * D_MODEL / 4;
  const float qscale = 0.125f * 1.44269504088896f;
  split4_kernel<<<n4x/256, 256, 0, stream>>>(x, x_hi, x_lo, n4x, 1.0f);
  prep_w_kernel<<<n4w/256, 256, 0, stream>>>(pq, pk, pv, po,
                                             wq_hi, wq_lo, wk_hi, wk_lo, wv_h, wo_h,
                                             n4w, qscale);

  // fused Q+K projection (shares the x tiles)
  gemm_qk<<<dim3(16, 32), 256, 0, stream>>>(x_hi, x_lo, wq_hi, wq_lo, wk_hi, wk_lo,
                                            q_hi, q_lo, k_hi, k_lo);
  // V projection with transposed output: VT[m][n] = sum_k wv[m][k] x[n][k]
  dim3 gv(NROWS/64, D_MODEL/128);  // (64, 8) -- col-chunked XCD swizzle
  gemm_nt<false, true><<<gv, 256, 0, stream>>>(wv_h, x_hi, vt, nullptr, D_MODEL, NROWS, D_MODEL);

  attn_kernel<<<dim3(512), 512, 0, stream>>>(q_hi, q_lo, k_hi, k_lo, vt, ao);

  dim3 gg(D_MODEL/64, NROWS/128);  // (16, 32)
  gemm_nt<true, false><<<gg, 256, 0, stream>>>(ao, wo_h, nullptr, out, NROWS, D_MODEL, D_MODEL);
}